// Round 3
// baseline (1392.698 us; speedup 1.0000x reference)
//
#include <hip/hip_runtime.h>
#include <math.h>

// FourRegionAttention on MI355X (gfx950), fp32 throughout.
// B=64, n=2304 (48x48), D=64, heads=8, hd=8.
// Requires ~158 MB of d_ws.

#define SCALE_W  0.3535533905932738f   // 8^-0.5
#define SCALE_RA 0.3535533905932738f
#define LN_EPS 1e-5f

// ---- workspace layout (float offsets) ----
#define OFF_XN   0ull
#define SZ_XN    (64ull*2304*64)            // 9437184
#define OFF_KT   (OFF_XN + SZ_XN)           // k_t [b][h][n][8]
#define SZ_KT    (64ull*8*2304*8)           // 9437184
#define OFF_VT   (OFF_KT + SZ_KT)           // v_t [b][h][n][8]
#define OFF_PG   (OFF_VT + SZ_KT)           // P [b][h][49][49][9]
#define SZ_PG    (512ull*49*49*9)           // 11063808
#define OFF_ECLS (OFF_PG + SZ_PG)           // 512
#define OFF_QC   (OFF_ECLS + 512)           // 64 (scaled q_c)
#define OFF_KC   (OFF_QC + 64)              // 64
#define OFF_VC   (OFF_KC + 64)              // 64
#define OFF_CLOG (OFF_VC + 64)              // 8
#define OFF_BK   (OFF_CLOG + 8)             // 64
#define OFF_BV   (OFF_BK + 64)              // 64
#define OFF_AH   (OFF_BV + 64)              // 512 a_h = Wraq@bqkv_h
#define OFF_W1   (OFF_AH + 512)             // 64  Wraq^T@bk
#define OFF_WZ   (OFF_W1 + 64)              // 64  Wrao@bv
#define OFF_B2   (OFF_WZ + 64)              // 512 Wrak^T@a_h
#define OFF_V2   (OFF_B2 + 512)             // 512 v2_h
#define OFF_UH   (OFF_V2 + 512)             // 512 u_h (unused in k_main; s0 cancels in softmax)
#define OFF_CH   (OFF_UH + 512)             // 8   c_h (unused in k_main)
#define OFF_C1   (OFF_CH + 8)               // 64  const output bias
#define OFF_KQ   (OFF_C1 + 64)              // 4096 Wraq^T@Wrak
#define OFF_WVE  (OFF_KQ + 4096)            // 4096 Wrav@Wwproj
#define OFF_KQP  (OFF_WVE + 4096)           // 4096 KQ@Wwproj
#define OFF_RW   (OFF_KQP + 4096)           // 4096 Wrao@WVE
#define OFF_G    (OFF_RW + 4096)            // 8*4096 G[h][d][e]
#define OFF_Z    (OFF_G + 32768)            // 8*4096 Zt[h][d][e] = Z_h[e][d]

// ---------------- setup kernels ----------------
__global__ void k_setup1(const float* __restrict__ Wqkv, const float* __restrict__ bqkv,
                         const float* __restrict__ cls_tok, const float* __restrict__ Wwqkv,
                         const float* __restrict__ bwqkv, const float* __restrict__ Wwproj,
                         const float* __restrict__ bwproj, const float* __restrict__ Wraq,
                         const float* __restrict__ Wrak, const float* __restrict__ Wrav,
                         const float* __restrict__ Wrao, const float* __restrict__ brao,
                         const float* __restrict__ Wout, const float* __restrict__ bout,
                         float* __restrict__ ws) {
  int tid = threadIdx.x;
  // phase1: cls_qkv (192), bk(64), bv(64), a_h(512)
  for (int idx = tid; idx < 832; idx += 256) {
    if (idx < 192) {
      float s = bwqkv[idx];
      for (int d = 0; d < 64; ++d) s += cls_tok[d] * Wwqkv[idx*64 + d];
      if (idx < 64) ws[OFF_QC + idx] = s * SCALE_W;
      else if (idx < 128) ws[OFF_KC + idx - 64] = s;
      else ws[OFF_VC + idx - 128] = s;
    } else if (idx < 256) {
      int e = idx - 192; float s = 0.f;
      for (int d = 0; d < 64; ++d) s += Wrak[e*64+d] * bwproj[d];
      ws[OFF_BK + e] = s;
    } else if (idx < 320) {
      int e = idx - 256; float s = 0.f;
      for (int d = 0; d < 64; ++d) s += Wrav[e*64+d] * bwproj[d];
      ws[OFF_BV + e] = s;
    } else {
      int t2 = idx - 320; int hh = t2 >> 6, e = t2 & 63; float s = 0.f;
      for (int d = 0; d < 64; ++d) s += Wraq[e*64+d] * bqkv[hh*64+d];
      ws[OFF_AH + t2] = s;
    }
  }
  __syncthreads();
  // phase2: cls_logit(8), wz(64), b2(512)
  for (int idx = tid; idx < 656; idx += 256) {
    if (idx < 8) {
      float s = 0.f;
      for (int u = 0; u < 8; ++u) s += ws[OFF_QC + idx*8+u] * ws[OFF_KC + idx*8+u];
      ws[OFF_CLOG + idx] = s;
    } else if (idx < 72) {
      int e = idx - 8; float s = 0.f;
      for (int d = 0; d < 64; ++d) s += Wraq[d*64+e] * ws[OFF_BK + d];
      ws[OFF_W1 + e] = s;
    } else if (idx < 136) {
      int e = idx - 72; float s = 0.f;
      for (int d = 0; d < 64; ++d) s += Wrao[e*64+d] * ws[OFF_BV + d];
      ws[OFF_WZ + e] = s;
    } else if (idx < 648) {
      int t2 = idx - 136; int hh = t2 >> 6, e = t2 & 63; float s = 0.f;
      for (int d = 0; d < 64; ++d) s += Wrak[d*64+e] * ws[OFF_AH + hh*64+d];
      ws[OFF_B2 + t2] = s;
    } else {
      int hh = idx - 648; float s = 0.f;
      for (int e = 0; e < 64; ++e) s += ws[OFF_AH + hh*64+e] * ws[OFF_BK + e];
      ws[OFF_CH + hh] = s;
    }
  }
  __syncthreads();
  // phase3: v2(512), uh(512), const1(64)
  for (int idx = tid; idx < 1088; idx += 256) {
    if (idx < 512) {
      int hh = idx >> 6, e = idx & 63; float s = 0.f;
      for (int d = 0; d < 64; ++d) s += Wwproj[d*64+e] * ws[OFF_B2 + hh*64+d];
      ws[OFF_V2 + idx] = s;
    } else if (idx < 1024) {
      int t2 = idx - 512; int hh = t2 >> 6, e = t2 & 63; float s = 0.f;
      for (int d = 0; d < 64; ++d) s += Wqkv[(hh*64+d)*64 + e] * ws[OFF_W1 + d];
      ws[OFF_UH + t2] = s;
    } else {
      int e = idx - 1024; float s = bout[e];
      for (int f = 0; f < 512; ++f)
        s += Wout[e*512+f] * (brao[f & 63] + ws[OFF_WZ + (f & 63)]);
      ws[OFF_C1 + e] = s;
    }
  }
}

__global__ void k_setup2(const float* __restrict__ Wraq, const float* __restrict__ Wrak,
                         const float* __restrict__ Wrav, const float* __restrict__ Wwproj,
                         float* __restrict__ ws) {
  int tid = threadIdx.x; int which = blockIdx.x;
  for (int t = tid; t < 4096; t += 256) {
    int i2 = t >> 6, j2 = t & 63; float s = 0.f;
    if (which == 0) { // KQ[d][e] = sum_f Wraq[f][d]*Wrak[f][e]
      for (int f = 0; f < 64; ++f) s += Wraq[f*64+i2] * Wrak[f*64+j2];
      ws[OFF_KQ + t] = s;
    } else {          // WVE[e][d] = sum_f Wrav[e][f]*Wwproj[f][d]
      for (int f = 0; f < 64; ++f) s += Wrav[i2*64+f] * Wwproj[f*64+j2];
      ws[OFF_WVE + t] = s;
    }
  }
}

__global__ void k_setup3(const float* __restrict__ Wwproj, const float* __restrict__ Wrao,
                         float* __restrict__ ws) {
  int tid = threadIdx.x; int which = blockIdx.x;
  for (int t = tid; t < 4096; t += 256) {
    int i2 = t >> 6, j2 = t & 63; float s = 0.f;
    if (which == 0) { // KQP = KQ @ Wwproj
      for (int f = 0; f < 64; ++f) s += ws[OFF_KQ + i2*64 + f] * Wwproj[f*64 + j2];
      ws[OFF_KQP + t] = s;
    } else {          // RW = Wrao @ WVE
      for (int f = 0; f < 64; ++f) s += Wrao[i2*64 + f] * ws[OFF_WVE + f*64 + j2];
      ws[OFF_RW + t] = s;
    }
  }
}

__global__ void k_setup4(const float* __restrict__ Wqkv, const float* __restrict__ Wout,
                         float* __restrict__ ws) {
  int tid = threadIdx.x; int blk = blockIdx.x;
  if (blk < 8) {       // G[h][d][e] = sum_f Wqkv[(h*64+f)][d] * KQP[f][e]
    int hh = blk;
    for (int t = tid; t < 4096; t += 256) {
      int d2 = t >> 6, e2 = t & 63; float s = 0.f;
      for (int f = 0; f < 64; ++f) s += Wqkv[(hh*64+f)*64 + d2] * ws[OFF_KQP + f*64 + e2];
      ws[OFF_G + hh*4096 + t] = s;
    }
  } else {             // Zt[h][d][e] = Z_h[e][d] = sum_f Wout[e][h*64+f] * RW[f][d]
    int hh = blk - 8;
    for (int t = tid; t < 4096; t += 256) {
      int d2 = t >> 6, e2 = t & 63; float s = 0.f;
      for (int f = 0; f < 64; ++f) s += Wout[e2*512 + hh*64 + f] * ws[OFF_RW + f*64 + d2];
      ws[OFF_Z + hh*4096 + t] = s;
    }
  }
}

// ---------------- LayerNorm + k/v GEMM ----------------
// grid 2304 blocks x 256 threads, 64 tokens/block
__global__ __launch_bounds__(256) void k_lnkv(const float* __restrict__ x,
      const float* __restrict__ ln_g, const float* __restrict__ ln_b,
      const float* __restrict__ Wwqkv, const float* __restrict__ bwqkv,
      float* __restrict__ ws) {
  __shared__ float sm[4352 + 8448 + 128];
  float* xnT = sm;                // [d][68] transposed xn tile
  float* xt  = sm + 4352;         // [tok][65]   (aliased by wkv later)
  float* wkv = sm + 4352;         // [d][132]
  float* muL = sm + 4352 + 8448;  // [64]
  float* rsL = muL + 64;          // [64]

  int tid = threadIdx.x;
  long T0 = (long)blockIdx.x * 64;
  int tok = tid >> 2, seg = tid & 3;

  // load x tile
  const float4* x4 = (const float4*)(x + (T0 + tok)*64 + seg*16);
  float4 va = x4[0], vb = x4[1], vc4 = x4[2], vd = x4[3];
  {
    float* xp = xt + tok*65 + seg*16;
    xp[0]=va.x; xp[1]=va.y; xp[2]=va.z; xp[3]=va.w;
    xp[4]=vb.x; xp[5]=vb.y; xp[6]=vb.z; xp[7]=vb.w;
    xp[8]=vc4.x; xp[9]=vc4.y; xp[10]=vc4.z; xp[11]=vc4.w;
    xp[12]=vd.x; xp[13]=vd.y; xp[14]=vd.z; xp[15]=vd.w;
  }
  __syncthreads();
  if (tid < 64) {
    float s = 0.f;
    for (int i2 = 0; i2 < 64; ++i2) s += xt[tid*65 + i2];
    float mu = s * (1.0f/64.0f);
    float v = 0.f;
    for (int i2 = 0; i2 < 64; ++i2) { float d = xt[tid*65 + i2] - mu; v += d*d; }
    v *= (1.0f/64.0f);
    muL[tid] = mu; rsL[tid] = 1.0f / sqrtf(v + LN_EPS);
  }
  __syncthreads();
  {
    float mu = muL[tok], rs = rsL[tok];
    float xv[16];
    #pragma unroll
    for (int k = 0; k < 16; ++k) {
      int i2 = seg*16 + k;
      float v = (xt[tok*65 + i2] - mu) * rs * ln_g[i2] + ln_b[i2];
      xv[k] = v;
      xnT[i2*68 + tok] = v;
    }
    float4* xng = (float4*)(ws + OFF_XN + (T0 + tok)*64 + seg*16);
    xng[0] = make_float4(xv[0], xv[1], xv[2], xv[3]);
    xng[1] = make_float4(xv[4], xv[5], xv[6], xv[7]);
    xng[2] = make_float4(xv[8], xv[9], xv[10], xv[11]);
    xng[3] = make_float4(xv[12], xv[13], xv[14], xv[15]);
  }
  __syncthreads();  // xt dead; load weights into union region
  {
    int o = tid >> 1, dh = (tid & 1) * 32;
    #pragma unroll
    for (int k = 0; k < 32; k += 4) {
      float4 w4 = *(const float4*)(Wwqkv + (64 + o)*64 + dh + k);
      wkv[(dh+k+0)*132 + o] = w4.x;
      wkv[(dh+k+1)*132 + o] = w4.y;
      wkv[(dh+k+2)*132 + o] = w4.z;
      wkv[(dh+k+3)*132 + o] = w4.w;
    }
  }
  __syncthreads();
  // GEMM: 64 tok x 128 out
  int tokq = tid & 15, og = tid >> 4;
  float acc[4][8];
  #pragma unroll
  for (int ti = 0; ti < 4; ++ti)
    #pragma unroll
    for (int k = 0; k < 8; ++k) acc[ti][k] = 0.f;
  for (int d2 = 0; d2 < 64; ++d2) {
    float4 a4 = *(float4*)&xnT[d2*68 + tokq*4];
    float4 b0 = *(float4*)&wkv[d2*132 + og*8];
    float4 b1 = *(float4*)&wkv[d2*132 + og*8 + 4];
    float aa[4] = {a4.x, a4.y, a4.z, a4.w};
    float bbv[8] = {b0.x,b0.y,b0.z,b0.w,b1.x,b1.y,b1.z,b1.w};
    #pragma unroll
    for (int ti = 0; ti < 4; ++ti)
      #pragma unroll
      for (int k = 0; k < 8; ++k) acc[ti][k] += aa[ti]*bbv[k];
  }
  int hh2 = og & 7;
  float bsv[8];
  #pragma unroll
  for (int k = 0; k < 8; ++k) bsv[k] = bwqkv[64 + og*8 + k];
  unsigned long long dstoff = (og < 8) ? OFF_KT : OFF_VT;
  #pragma unroll
  for (int ti = 0; ti < 4; ++ti) {
    long ntok = T0 + tokq*4 + ti;
    int bb = (int)(ntok / 2304);
    int nl = (int)(ntok % 2304);
    float* dst = ws + dstoff + ((long)(bb*8 + hh2)*2304 + nl)*8;
    *(float4*)dst = make_float4(acc[ti][0]+bsv[0], acc[ti][1]+bsv[1], acc[ti][2]+bsv[2], acc[ti][3]+bsv[3]);
    *(float4*)(dst+4) = make_float4(acc[ti][4]+bsv[4], acc[ti][5]+bsv[5], acc[ti][6]+bsv[6], acc[ti][7]+bsv[7]);
  }
}

// ---------------- logits + softmax-normalizer + 2D prefix sums ----------------
// grid 1024: blk = (bh<<1)|g ; g selects channel half. 256 threads.
__global__ __launch_bounds__(256) void k_prefix(float* __restrict__ ws) {
  __shared__ float lg[2304];
  __shared__ float Pp[49*49*5];
  __shared__ float red[256];
  int tid = threadIdx.x;
  int blk = blockIdx.x;
  int g = blk & 1, bh = blk >> 1;
  int hh = bh & 7;
  const float* kt = ws + OFF_KT + (long)bh*2304*8;
  const float* vt = ws + OFF_VT + (long)bh*2304*8 + (g ? 4 : 0);
  float qc[8];
  #pragma unroll
  for (int u = 0; u < 8; ++u) qc[u] = ws[OFF_QC + hh*8 + u];
  float mloc = -1e30f;
  #pragma unroll
  for (int it = 0; it < 9; ++it) {
    int nn = tid + it*256;
    const float4* kk = (const float4*)(kt + nn*8);
    float4 k0 = kk[0], k1 = kk[1];
    float lv = qc[0]*k0.x + qc[1]*k0.y + qc[2]*k0.z + qc[3]*k0.w
             + qc[4]*k1.x + qc[5]*k1.y + qc[6]*k1.z + qc[7]*k1.w;
    lg[nn] = lv;
    mloc = fmaxf(mloc, lv);
  }
  red[tid] = mloc;
  __syncthreads();
  for (int s2 = 128; s2 > 0; s2 >>= 1) {
    if (tid < s2) red[tid] = fmaxf(red[tid], red[tid + s2]);
    __syncthreads();
  }
  float m = fmaxf(red[0], ws[OFF_CLOG + hh]);
  if (tid == 0 && g == 0) ws[OFF_ECLS + bh] = expf(ws[OFF_CLOG + hh] - m);
  #pragma unroll
  for (int it = 0; it < 9; ++it) {
    int nn = tid + it*256;
    lg[nn] = expf(lg[nn] - m);
  }
  // zero P
  for (int idx = tid; idx < 49*49*5; idx += 256) Pp[idx] = 0.f;
  __syncthreads();
  int nc = g ? 4 : 5;
  #pragma unroll
  for (int it = 0; it < 9; ++it) {
    int nn = tid + it*256;
    int i2 = nn / 48, j2 = nn % 48;
    float ev = lg[nn];
    float4 v4 = *(const float4*)(vt + nn*8);
    float* cell = &Pp[((i2+1)*49 + (j2+1))*5];
    if (g == 0) {
      cell[0] = ev; cell[1] = ev*v4.x; cell[2] = ev*v4.y; cell[3] = ev*v4.z; cell[4] = ev*v4.w;
    } else {
      cell[0] = ev*v4.x; cell[1] = ev*v4.y; cell[2] = ev*v4.z; cell[3] = ev*v4.w;
    }
  }
  __syncthreads();
  // vertical cumsum (axis i) -- matches reference axis=2-first order
  for (int idx = tid; idx < 48*nc; idx += 256) {
    int j2 = idx / nc + 1, c = idx % nc;
    for (int i2 = 2; i2 <= 48; ++i2)
      Pp[(i2*49 + j2)*5 + c] += Pp[((i2-1)*49 + j2)*5 + c];
  }
  __syncthreads();
  // horizontal cumsum (axis j)
  for (int idx = tid; idx < 48*nc; idx += 256) {
    int i2 = idx / nc + 1, c = idx % nc;
    for (int j2 = 2; j2 <= 48; ++j2)
      Pp[(i2*49 + j2)*5 + c] += Pp[(i2*49 + j2 - 1)*5 + c];
  }
  __syncthreads();
  // write out P [49][49][9]
  float* pg = ws + OFF_PG + (long)bh*21609;
  int tot = 2401 * nc;
  for (int idx = tid; idx < tot; idx += 256) {
    int cell2 = idx / nc, c = idx % nc;
    pg[cell2*9 + (g ? 5 + c : c)] = Pp[cell2*5 + c];
  }
}

// ---------------- main fused kernel ----------------
// grid 4608 blocks x 256 threads, 32 tokens/block.
// tid = tok*8 + eg: all 8 channel-groups of a token live in one 8-lane group
// of one wave. cls/xn/cbar stay in registers; cross-channel exchange is done
// with width-8 shuffles (ds_bpermute). ZERO LDS, ZERO __syncthreads.
// s0 (qp.bk bias) is region-independent and cancels in the softmax -> dropped.
__global__ __launch_bounds__(256) void k_main(const float* __restrict__ ws,
                                              float* __restrict__ outp) {
  int tid = threadIdx.x;
  int tok = tid >> 3, eg = tid & 7;
  long T0 = (long)blockIdx.x * 32;
  int b = (int)(T0 / 2304);
  int n = (int)(T0 % 2304) + tok;
  int i2 = n / 48, j2 = n % 48;

  // xn slice (channels eg*8..+8 of this token) -> registers
  float xr[8];
  {
    const float4* p4 = (const float4*)(ws + OFF_XN + (T0 + tok)*64 + eg*8);
    float4 xa = p4[0], xb = p4[1];
    xr[0]=xa.x; xr[1]=xa.y; xr[2]=xa.z; xr[3]=xa.w;
    xr[4]=xb.x; xr[5]=xb.y; xr[6]=xb.z; xr[7]=xb.w;
  }

  // phase0: this thread's cls slice (head eg, channels eg*8..+8, 4 regions)
  float cls0[8], cls1[8], cls2[8], cls3[8];
  {
    float ec = ws[OFF_ECLS + b*8 + eg];
    const float* P = ws + OFF_PG + ((long)(b*8 + eg))*21609;
    int p_ij  = (i2*49 + j2)*9;
    int p_ij1 = p_ij + 9;
    int p_iW  = (i2*49 + 48)*9;
    int p_1j  = ((i2+1)*49 + j2)*9;
    int p_1j1 = p_1j + 9;
    int p_1W  = ((i2+1)*49 + 48)*9;
    int p_Hj  = (48*49 + j2)*9;
    int p_Hj1 = p_Hj + 9;
    int p_HW  = (48*49 + 48)*9;
    float rden[4];
    {
      float tl = P[p_1j1];
      float tr = P[p_1W] - P[p_1j];
      float bl = P[p_Hj1] - P[p_ij1];
      float br = P[p_HW] - P[p_iW] - P[p_Hj] + P[p_ij];
      rden[0] = 1.0f/(ec + tl); rden[1] = 1.0f/(ec + tr);
      rden[2] = 1.0f/(ec + bl); rden[3] = 1.0f/(ec + br);
    }
    #pragma unroll
    for (int u = 0; u < 8; ++u) {
      int c = 1 + u;
      float tl = P[p_1j1 + c];
      float tr = P[p_1W + c] - P[p_1j + c];
      float bl = P[p_Hj1 + c] - P[p_ij1 + c];
      float br = P[p_HW + c] - P[p_iW + c] - P[p_Hj + c] + P[p_ij + c];
      float nv = ec * ws[OFF_VC + eg*8 + u];
      cls0[u] = (nv + tl) * rden[0];
      cls1[u] = (nv + tr) * rden[1];
      cls2[u] = (nv + bl) * rden[2];
      cls3[u] = (nv + br) * rden[3];
    }
  }

  float oacc[8];
  #pragma unroll
  for (int k = 0; k < 8; ++k) oacc[k] = 0.f;

  for (int hh = 0; hh < 8; ++hh) {
    // stage1: t_h[e] = sum_d G_h[d][e]*xn[d] (+v2) for e = eg*8..+8
    const float* Gp = ws + OFF_G + hh*4096 + eg*8;   // row stride 64 floats
    float acc[8];
    #pragma unroll
    for (int k = 0; k < 8; ++k) acc[k] = ws[OFF_V2 + hh*64 + eg*8 + k];
    for (int gb = 0; gb < 8; ++gb) {
      #pragma unroll
      for (int j = 0; j < 8; ++j) {
        int d2 = gb*8 + j;
        float xv = __shfl(xr[j], gb, 8);   // xn[d2] from lane (tok,eg=gb)
        float4 g0 = *(const float4*)(Gp + d2*64);
        float4 g1 = *(const float4*)(Gp + d2*64 + 4);
        acc[0] += xv*g0.x; acc[1] += xv*g0.y; acc[2] += xv*g0.z; acc[3] += xv*g0.w;
        acc[4] += xv*g1.x; acc[5] += xv*g1.y; acc[6] += xv*g1.z; acc[7] += xv*g1.w;
      }
    }
    // stage2: score partials + width-8 reduction + softmax (per lane)
    float p0 = 0.f, p1 = 0.f, p2 = 0.f, p3 = 0.f;
    #pragma unroll
    for (int k = 0; k < 8; ++k) {
      p0 += acc[k]*cls0[k]; p1 += acc[k]*cls1[k];
      p2 += acc[k]*cls2[k]; p3 += acc[k]*cls3[k];
    }
    #pragma unroll
    for (int mk = 1; mk < 8; mk <<= 1) {
      p0 += __shfl_xor(p0, mk, 8);
      p1 += __shfl_xor(p1, mk, 8);
      p2 += __shfl_xor(p2, mk, 8);
      p3 += __shfl_xor(p3, mk, 8);
    }
    float s0 = p0*SCALE_RA, s1 = p1*SCALE_RA, s2 = p2*SCALE_RA, s3 = p3*SCALE_RA;
    float mm = fmaxf(fmaxf(s0, s1), fmaxf(s2, s3));
    float e0 = expf(s0-mm), e1 = expf(s1-mm), e2 = expf(s2-mm), e3 = expf(s3-mm);
    float inv = 1.0f/(e0+e1+e2+e3);
    float av0 = e0*inv, av1 = e1*inv, av2 = e2*inv, av3 = e3*inv;
    // cbar slice (channels eg*8..+8) in registers
    float cb[8];
    #pragma unroll
    for (int k = 0; k < 8; ++k)
      cb[k] = av0*cls0[k] + av1*cls1[k] + av2*cls2[k] + av3*cls3[k];
    // stage3: out[e] += sum_d Z_h[e][d]*cbar[d], Zt[h][d][e] layout
    const float* Zp = ws + OFF_Z + hh*4096 + eg*8;
    for (int gb = 0; gb < 8; ++gb) {
      #pragma unroll
      for (int j = 0; j < 8; ++j) {
        int d2 = gb*8 + j;
        float cv = __shfl(cb[j], gb, 8);   // cbar[d2] from lane (tok,eg=gb)
        float4 z0 = *(const float4*)(Zp + d2*64);
        float4 z1 = *(const float4*)(Zp + d2*64 + 4);
        oacc[0] += cv*z0.x; oacc[1] += cv*z0.y; oacc[2] += cv*z0.z; oacc[3] += cv*z0.w;
        oacc[4] += cv*z1.x; oacc[5] += cv*z1.y; oacc[6] += cv*z1.z; oacc[7] += cv*z1.w;
      }
    }
  }
  // epilogue
  float4* dst = (float4*)(outp + (T0 + tok)*64 + eg*8);
  const float* co = ws + OFF_C1 + eg*8;
  dst[0] = make_float4(oacc[0]+co[0], oacc[1]+co[1], oacc[2]+co[2], oacc[3]+co[3]);
  dst[1] = make_float4(oacc[4]+co[4], oacc[5]+co[5], oacc[6]+co[6], oacc[7]+co[7]);
}

extern "C" void kernel_launch(void* const* d_in, const int* in_sizes, int n_in,
                              void* d_out, int out_size, void* d_ws, size_t ws_size,
                              hipStream_t stream) {
  const float* x      = (const float*)d_in[0];
  const float* ln_g   = (const float*)d_in[1];
  const float* ln_b   = (const float*)d_in[2];
  const float* Wqkv   = (const float*)d_in[3];
  const float* bqkv   = (const float*)d_in[4];
  const float* cls_tok= (const float*)d_in[5];
  const float* Wwqkv  = (const float*)d_in[6];
  const float* bwqkv  = (const float*)d_in[7];
  const float* Wwproj = (const float*)d_in[8];
  const float* bwproj = (const float*)d_in[9];
  const float* Wraq   = (const float*)d_in[10];
  const float* Wrak   = (const float*)d_in[11];
  const float* Wrav   = (const float*)d_in[12];
  const float* Wrao   = (const float*)d_in[13];
  const float* brao   = (const float*)d_in[14];
  const float* Wout   = (const float*)d_in[15];
  const float* bout   = (const float*)d_in[16];
  float* ws = (float*)d_ws;
  float* outp = (float*)d_out;

  hipLaunchKernelGGL(k_setup1, dim3(1), dim3(256), 0, stream,
                     Wqkv, bqkv, cls_tok, Wwqkv, bwqkv, Wwproj, bwproj,
                     Wraq, Wrak, Wrav, Wrao, brao, Wout, bout, ws);
  hipLaunchKernelGGL(k_setup2, dim3(2), dim3(256), 0, stream, Wraq, Wrak, Wrav, Wwproj, ws);
  hipLaunchKernelGGL(k_setup3, dim3(2), dim3(256), 0, stream, Wwproj, Wrao, ws);
  hipLaunchKernelGGL(k_setup4, dim3(16), dim3(256), 0, stream, Wqkv, Wout, ws);
  hipLaunchKernelGGL(k_lnkv, dim3(2304), dim3(256), 0, stream, x, ln_g, ln_b, Wwqkv, bwqkv, ws);
  hipLaunchKernelGGL(k_prefix, dim3(1024), dim3(256), 0, stream, ws);
  hipLaunchKernelGGL(k_main, dim3(4608), dim3(256), 0, stream, ws, outp);
}

// Round 4
// 645.616 us; speedup vs baseline: 2.1572x; 2.1572x over previous
//
#include <hip/hip_runtime.h>
#include <math.h>

// FourRegionAttention on MI355X (gfx950). B=64, n=2304 (48x48), D=64, h=8, hd=8.
// k_main: stage1/stage3 GEMMs via MFMA 16x16x32 bf16 with hi/lo split (3-product
// fp32 emulation); softmax/cbar in registers with width-8 shuffles.

#define SCALE_W  0.3535533905932738f   // 8^-0.5
#define SCALE_RA 0.3535533905932738f
#define LN_EPS 1e-5f

typedef __attribute__((ext_vector_type(8))) short bf16x8;
typedef __attribute__((ext_vector_type(4))) float f32x4;

// ---- workspace layout (float offsets) ----
#define OFF_XN   0ull
#define SZ_XN    (64ull*2304*64)            // 9437184
#define OFF_KT   (OFF_XN + SZ_XN)           // k_t [b][h][n][8]  (dead after k_prefix)
#define SZ_KT    (64ull*8*2304*8)           // 9437184
#define OFF_VT   (OFF_KT + SZ_KT)           // v_t [b][h][n][8]  (dead after k_prefix)
#define OFF_PG   (OFF_VT + SZ_KT)           // P [b][h][49][49][9]
#define SZ_PG    (512ull*49*49*9)           // 11063808
#define OFF_ECLS (OFF_PG + SZ_PG)           // 512
#define OFF_QC   (OFF_ECLS + 512)           // 64 (scaled q_c)
#define OFF_KC   (OFF_QC + 64)              // 64
#define OFF_VC   (OFF_KC + 64)              // 64
#define OFF_CLOG (OFF_VC + 64)              // 8
#define OFF_BK   (OFF_CLOG + 8)             // 64
#define OFF_BV   (OFF_BK + 64)              // 64
#define OFF_AH   (OFF_BV + 64)              // 512 a_h = Wraq@bqkv_h
#define OFF_W1   (OFF_AH + 512)             // 64  Wraq^T@bk
#define OFF_WZ   (OFF_W1 + 64)              // 64  Wrao@bv
#define OFF_B2   (OFF_WZ + 64)              // 512 Wrak^T@a_h
#define OFF_V2   (OFF_B2 + 512)             // 512 v2_h
#define OFF_UH   (OFF_V2 + 512)             // 512 (unused in k_main)
#define OFF_CH   (OFF_UH + 512)             // 8   (unused in k_main)
#define OFF_C1   (OFF_CH + 8)               // 64  const output bias
#define OFF_KQ   (OFF_C1 + 64)              // 4096 Wraq^T@Wrak
#define OFF_WVE  (OFF_KQ + 4096)            // 4096 Wrav@Wwproj
#define OFF_KQP  (OFF_WVE + 4096)           // 4096 KQ@Wwproj
#define OFF_RW   (OFF_KQP + 4096)           // 4096 Wrao@WVE
#define OFF_G    (OFF_RW + 4096)            // 8*4096 G[h][d][e]
#define OFF_Z    (OFF_G + 32768)            // 8*4096 Zt[h][d][e] = Z_h[e][d]
// bf16 hi/lo weights overlay the dead KT region (written after k_prefix):
// gb16: [h][split][e][d] ushort ; zb16 same. 8*2*4096 ushorts each.
#define OFF_GB   OFF_KT
#define OFF_ZB   (OFF_KT + 32768)

__device__ inline unsigned short bf16_rne(float x) {
  unsigned u = __float_as_uint(x);
  return (unsigned short)((u + 0x7fffu + ((u >> 16) & 1u)) >> 16);
}
__device__ inline void split2(float x, unsigned short &h, unsigned short &l) {
  unsigned u = __float_as_uint(x);
  unsigned hr = (u + 0x7fffu + ((u >> 16) & 1u)) >> 16;
  h = (unsigned short)hr;
  float hf = __uint_as_float(hr << 16);
  float lo = x - hf;
  unsigned u2 = __float_as_uint(lo);
  l = (unsigned short)((u2 + 0x7fffu + ((u2 >> 16) & 1u)) >> 16);
}

// ---------------- setup kernels ----------------
__global__ void k_setup1(const float* __restrict__ Wqkv, const float* __restrict__ bqkv,
                         const float* __restrict__ cls_tok, const float* __restrict__ Wwqkv,
                         const float* __restrict__ bwqkv, const float* __restrict__ Wwproj,
                         const float* __restrict__ bwproj, const float* __restrict__ Wraq,
                         const float* __restrict__ Wrak, const float* __restrict__ Wrav,
                         const float* __restrict__ Wrao, const float* __restrict__ brao,
                         const float* __restrict__ Wout, const float* __restrict__ bout,
                         float* __restrict__ ws) {
  int tid = threadIdx.x;
  for (int idx = tid; idx < 832; idx += 256) {
    if (idx < 192) {
      float s = bwqkv[idx];
      for (int d = 0; d < 64; ++d) s += cls_tok[d] * Wwqkv[idx*64 + d];
      if (idx < 64) ws[OFF_QC + idx] = s * SCALE_W;
      else if (idx < 128) ws[OFF_KC + idx - 64] = s;
      else ws[OFF_VC + idx - 128] = s;
    } else if (idx < 256) {
      int e = idx - 192; float s = 0.f;
      for (int d = 0; d < 64; ++d) s += Wrak[e*64+d] * bwproj[d];
      ws[OFF_BK + e] = s;
    } else if (idx < 320) {
      int e = idx - 256; float s = 0.f;
      for (int d = 0; d < 64; ++d) s += Wrav[e*64+d] * bwproj[d];
      ws[OFF_BV + e] = s;
    } else {
      int t2 = idx - 320; int hh = t2 >> 6, e = t2 & 63; float s = 0.f;
      for (int d = 0; d < 64; ++d) s += Wraq[e*64+d] * bqkv[hh*64+d];
      ws[OFF_AH + t2] = s;
    }
  }
  __syncthreads();
  for (int idx = tid; idx < 656; idx += 256) {
    if (idx < 8) {
      float s = 0.f;
      for (int u = 0; u < 8; ++u) s += ws[OFF_QC + idx*8+u] * ws[OFF_KC + idx*8+u];
      ws[OFF_CLOG + idx] = s;
    } else if (idx < 72) {
      int e = idx - 8; float s = 0.f;
      for (int d = 0; d < 64; ++d) s += Wraq[d*64+e] * ws[OFF_BK + d];
      ws[OFF_W1 + e] = s;
    } else if (idx < 136) {
      int e = idx - 72; float s = 0.f;
      for (int d = 0; d < 64; ++d) s += Wrao[e*64+d] * ws[OFF_BV + d];
      ws[OFF_WZ + e] = s;
    } else if (idx < 648) {
      int t2 = idx - 136; int hh = t2 >> 6, e = t2 & 63; float s = 0.f;
      for (int d = 0; d < 64; ++d) s += Wrak[d*64+e] * ws[OFF_AH + hh*64+d];
      ws[OFF_B2 + t2] = s;
    } else {
      int hh = idx - 648; float s = 0.f;
      for (int e = 0; e < 64; ++e) s += ws[OFF_AH + hh*64+e] * ws[OFF_BK + e];
      ws[OFF_CH + hh] = s;
    }
  }
  __syncthreads();
  for (int idx = tid; idx < 1088; idx += 256) {
    if (idx < 512) {
      int hh = idx >> 6, e = idx & 63; float s = 0.f;
      for (int d = 0; d < 64; ++d) s += Wwproj[d*64+e] * ws[OFF_B2 + hh*64+d];
      ws[OFF_V2 + idx] = s;
    } else if (idx < 1024) {
      int t2 = idx - 512; int hh = t2 >> 6, e = t2 & 63; float s = 0.f;
      for (int d = 0; d < 64; ++d) s += Wqkv[(hh*64+d)*64 + e] * ws[OFF_W1 + d];
      ws[OFF_UH + t2] = s;
    } else {
      int e = idx - 1024; float s = bout[e];
      for (int f = 0; f < 512; ++f)
        s += Wout[e*512+f] * (brao[f & 63] + ws[OFF_WZ + (f & 63)]);
      ws[OFF_C1 + e] = s;
    }
  }
}

__global__ void k_setup2(const float* __restrict__ Wraq, const float* __restrict__ Wrak,
                         const float* __restrict__ Wrav, const float* __restrict__ Wwproj,
                         float* __restrict__ ws) {
  int tid = threadIdx.x; int which = blockIdx.x;
  for (int t = tid; t < 4096; t += 256) {
    int i2 = t >> 6, j2 = t & 63; float s = 0.f;
    if (which == 0) {
      for (int f = 0; f < 64; ++f) s += Wraq[f*64+i2] * Wrak[f*64+j2];
      ws[OFF_KQ + t] = s;
    } else {
      for (int f = 0; f < 64; ++f) s += Wrav[i2*64+f] * Wwproj[f*64+j2];
      ws[OFF_WVE + t] = s;
    }
  }
}

__global__ void k_setup3(const float* __restrict__ Wwproj, const float* __restrict__ Wrao,
                         float* __restrict__ ws) {
  int tid = threadIdx.x; int which = blockIdx.x;
  for (int t = tid; t < 4096; t += 256) {
    int i2 = t >> 6, j2 = t & 63; float s = 0.f;
    if (which == 0) {
      for (int f = 0; f < 64; ++f) s += ws[OFF_KQ + i2*64 + f] * Wwproj[f*64 + j2];
      ws[OFF_KQP + t] = s;
    } else {
      for (int f = 0; f < 64; ++f) s += Wrao[i2*64 + f] * ws[OFF_WVE + f*64 + j2];
      ws[OFF_RW + t] = s;
    }
  }
}

__global__ void k_setup4(const float* __restrict__ Wqkv, const float* __restrict__ Wout,
                         float* __restrict__ ws) {
  int tid = threadIdx.x; int blk = blockIdx.x;
  if (blk < 8) {       // G[h][d][e]
    int hh = blk;
    for (int t = tid; t < 4096; t += 256) {
      int d2 = t >> 6, e2 = t & 63; float s = 0.f;
      for (int f = 0; f < 64; ++f) s += Wqkv[(hh*64+f)*64 + d2] * ws[OFF_KQP + f*64 + e2];
      ws[OFF_G + hh*4096 + t] = s;
    }
  } else {             // Zt[h][d][e] = Z_h[e][d]
    int hh = blk - 8;
    for (int t = tid; t < 4096; t += 256) {
      int d2 = t >> 6, e2 = t & 63; float s = 0.f;
      for (int f = 0; f < 64; ++f) s += Wout[e2*512 + hh*64 + f] * ws[OFF_RW + f*64 + d2];
      ws[OFF_Z + hh*4096 + t] = s;
    }
  }
}

// split G/Z into bf16 hi/lo, transposed to [e][d] (B-operand friendly).
// Runs AFTER k_prefix (overlays dead k_t region). grid 16.
__global__ void k_setup5(float* __restrict__ ws) {
  int hh = blockIdx.x >> 1; int isZ = blockIdx.x & 1;
  const float* src = ws + (isZ ? OFF_Z : OFF_G) + hh*4096;   // [d][e]
  unsigned short* dst = (unsigned short*)(ws + (isZ ? OFF_ZB : OFF_GB)) + hh*8192;
  for (int t = threadIdx.x; t < 4096; t += 256) {
    int d = t >> 6, e = t & 63;
    unsigned short h, l;
    split2(src[d*64 + e], h, l);
    dst[e*64 + d] = h;
    dst[4096 + e*64 + d] = l;
  }
}

// ---------------- LayerNorm + k/v GEMM ----------------
__global__ __launch_bounds__(256) void k_lnkv(const float* __restrict__ x,
      const float* __restrict__ ln_g, const float* __restrict__ ln_b,
      const float* __restrict__ Wwqkv, const float* __restrict__ bwqkv,
      float* __restrict__ ws) {
  __shared__ float sm[4352 + 8448 + 128];
  float* xnT = sm;                // [d][68]
  float* xt  = sm + 4352;         // [tok][65]
  float* wkv = sm + 4352;         // [d][132]
  float* muL = sm + 4352 + 8448;
  float* rsL = muL + 64;

  int tid = threadIdx.x;
  long T0 = (long)blockIdx.x * 64;
  int tok = tid >> 2, seg = tid & 3;

  const float4* x4 = (const float4*)(x + (T0 + tok)*64 + seg*16);
  float4 va = x4[0], vb = x4[1], vc4 = x4[2], vd = x4[3];
  {
    float* xp = xt + tok*65 + seg*16;
    xp[0]=va.x; xp[1]=va.y; xp[2]=va.z; xp[3]=va.w;
    xp[4]=vb.x; xp[5]=vb.y; xp[6]=vb.z; xp[7]=vb.w;
    xp[8]=vc4.x; xp[9]=vc4.y; xp[10]=vc4.z; xp[11]=vc4.w;
    xp[12]=vd.x; xp[13]=vd.y; xp[14]=vd.z; xp[15]=vd.w;
  }
  __syncthreads();
  if (tid < 64) {
    float s = 0.f;
    for (int i2 = 0; i2 < 64; ++i2) s += xt[tid*65 + i2];
    float mu = s * (1.0f/64.0f);
    float v = 0.f;
    for (int i2 = 0; i2 < 64; ++i2) { float d = xt[tid*65 + i2] - mu; v += d*d; }
    v *= (1.0f/64.0f);
    muL[tid] = mu; rsL[tid] = 1.0f / sqrtf(v + LN_EPS);
  }
  __syncthreads();
  {
    float mu = muL[tok], rs = rsL[tok];
    float xv[16];
    #pragma unroll
    for (int k = 0; k < 16; ++k) {
      int i2 = seg*16 + k;
      float v = (xt[tok*65 + i2] - mu) * rs * ln_g[i2] + ln_b[i2];
      xv[k] = v;
      xnT[i2*68 + tok] = v;
    }
    float4* xng = (float4*)(ws + OFF_XN + (T0 + tok)*64 + seg*16);
    xng[0] = make_float4(xv[0], xv[1], xv[2], xv[3]);
    xng[1] = make_float4(xv[4], xv[5], xv[6], xv[7]);
    xng[2] = make_float4(xv[8], xv[9], xv[10], xv[11]);
    xng[3] = make_float4(xv[12], xv[13], xv[14], xv[15]);
  }
  __syncthreads();
  {
    int o = tid >> 1, dh = (tid & 1) * 32;
    #pragma unroll
    for (int k = 0; k < 32; k += 4) {
      float4 w4 = *(const float4*)(Wwqkv + (64 + o)*64 + dh + k);
      wkv[(dh+k+0)*132 + o] = w4.x;
      wkv[(dh+k+1)*132 + o] = w4.y;
      wkv[(dh+k+2)*132 + o] = w4.z;
      wkv[(dh+k+3)*132 + o] = w4.w;
    }
  }
  __syncthreads();
  int tokq = tid & 15, og = tid >> 4;
  float acc[4][8];
  #pragma unroll
  for (int ti = 0; ti < 4; ++ti)
    #pragma unroll
    for (int k = 0; k < 8; ++k) acc[ti][k] = 0.f;
  for (int d2 = 0; d2 < 64; ++d2) {
    float4 a4 = *(float4*)&xnT[d2*68 + tokq*4];
    float4 b0 = *(float4*)&wkv[d2*132 + og*8];
    float4 b1 = *(float4*)&wkv[d2*132 + og*8 + 4];
    float aa[4] = {a4.x, a4.y, a4.z, a4.w};
    float bbv[8] = {b0.x,b0.y,b0.z,b0.w,b1.x,b1.y,b1.z,b1.w};
    #pragma unroll
    for (int ti = 0; ti < 4; ++ti)
      #pragma unroll
      for (int k = 0; k < 8; ++k) acc[ti][k] += aa[ti]*bbv[k];
  }
  int hh2 = og & 7;
  float bsv[8];
  #pragma unroll
  for (int k = 0; k < 8; ++k) bsv[k] = bwqkv[64 + og*8 + k];
  unsigned long long dstoff = (og < 8) ? OFF_KT : OFF_VT;
  #pragma unroll
  for (int ti = 0; ti < 4; ++ti) {
    long ntok = T0 + tokq*4 + ti;
    int bb = (int)(ntok / 2304);
    int nl = (int)(ntok % 2304);
    float* dst = ws + dstoff + ((long)(bb*8 + hh2)*2304 + nl)*8;
    *(float4*)dst = make_float4(acc[ti][0]+bsv[0], acc[ti][1]+bsv[1], acc[ti][2]+bsv[2], acc[ti][3]+bsv[3]);
    *(float4*)(dst+4) = make_float4(acc[ti][4]+bsv[4], acc[ti][5]+bsv[5], acc[ti][6]+bsv[6], acc[ti][7]+bsv[7]);
  }
}

// ---------------- logits + softmax-normalizer + 2D prefix sums ----------------
__global__ __launch_bounds__(256) void k_prefix(float* __restrict__ ws) {
  __shared__ float lg[2304];
  __shared__ float Pp[49*49*5];
  __shared__ float red[256];
  int tid = threadIdx.x;
  int blk = blockIdx.x;
  int g = blk & 1, bh = blk >> 1;
  int hh = bh & 7;
  const float* kt = ws + OFF_KT + (long)bh*2304*8;
  const float* vt = ws + OFF_VT + (long)bh*2304*8 + (g ? 4 : 0);
  float qc[8];
  #pragma unroll
  for (int u = 0; u < 8; ++u) qc[u] = ws[OFF_QC + hh*8 + u];
  float mloc = -1e30f;
  #pragma unroll
  for (int it = 0; it < 9; ++it) {
    int nn = tid + it*256;
    const float4* kk = (const float4*)(kt + nn*8);
    float4 k0 = kk[0], k1 = kk[1];
    float lv = qc[0]*k0.x + qc[1]*k0.y + qc[2]*k0.z + qc[3]*k0.w
             + qc[4]*k1.x + qc[5]*k1.y + qc[6]*k1.z + qc[7]*k1.w;
    lg[nn] = lv;
    mloc = fmaxf(mloc, lv);
  }
  red[tid] = mloc;
  __syncthreads();
  for (int s2 = 128; s2 > 0; s2 >>= 1) {
    if (tid < s2) red[tid] = fmaxf(red[tid], red[tid + s2]);
    __syncthreads();
  }
  float m = fmaxf(red[0], ws[OFF_CLOG + hh]);
  if (tid == 0 && g == 0) ws[OFF_ECLS + bh] = expf(ws[OFF_CLOG + hh] - m);
  #pragma unroll
  for (int it = 0; it < 9; ++it) {
    int nn = tid + it*256;
    lg[nn] = expf(lg[nn] - m);
  }
  for (int idx = tid; idx < 49*49*5; idx += 256) Pp[idx] = 0.f;
  __syncthreads();
  int nc = g ? 4 : 5;
  #pragma unroll
  for (int it = 0; it < 9; ++it) {
    int nn = tid + it*256;
    int i2 = nn / 48, j2 = nn % 48;
    float ev = lg[nn];
    float4 v4 = *(const float4*)(vt + nn*8);
    float* cell = &Pp[((i2+1)*49 + (j2+1))*5];
    if (g == 0) {
      cell[0] = ev; cell[1] = ev*v4.x; cell[2] = ev*v4.y; cell[3] = ev*v4.z; cell[4] = ev*v4.w;
    } else {
      cell[0] = ev*v4.x; cell[1] = ev*v4.y; cell[2] = ev*v4.z; cell[3] = ev*v4.w;
    }
  }
  __syncthreads();
  for (int idx = tid; idx < 48*nc; idx += 256) {
    int j2 = idx / nc + 1, c = idx % nc;
    for (int i2 = 2; i2 <= 48; ++i2)
      Pp[(i2*49 + j2)*5 + c] += Pp[((i2-1)*49 + j2)*5 + c];
  }
  __syncthreads();
  for (int idx = tid; idx < 48*nc; idx += 256) {
    int i2 = idx / nc + 1, c = idx % nc;
    for (int j2 = 2; j2 <= 48; ++j2)
      Pp[(i2*49 + j2)*5 + c] += Pp[(i2*49 + j2 - 1)*5 + c];
  }
  __syncthreads();
  float* pg = ws + OFF_PG + (long)bh*21609;
  int tot = 2401 * nc;
  for (int idx = tid; idx < tot; idx += 256) {
    int cell2 = idx / nc, c = idx % nc;
    pg[cell2*9 + (g ? 5 + c : c)] = Pp[cell2*5 + c];
  }
}

// ---------------- main fused kernel (MFMA) ----------------
// grid 4608 x 256 threads, 32 tokens/block. LDS 26112 B.
__global__ __launch_bounds__(256) void k_main(const float* __restrict__ ws,
                                              float* __restrict__ outp) {
  __shared__ __align__(16) unsigned short XNhi[32*68];
  __shared__ __align__(16) unsigned short XNlo[32*68];
  __shared__ __align__(16) unsigned short CBhi[32*68];
  __shared__ __align__(16) unsigned short CBlo[32*68];
  __shared__ __align__(16) float Tlds[32*68];

  int tid = threadIdx.x;
  int tok = tid >> 3, eg = tid & 7;
  int lane = tid & 63, wv = tid >> 6;
  int quad = lane >> 4, lrow = lane & 15;
  int rowblk = wv >> 1, colb0 = (wv & 1) * 2;
  long T0 = (long)blockIdx.x * 32;
  int b = (int)(T0 / 2304);
  int n = (int)(T0 % 2304) + tok;
  int i2 = n / 48, j2 = n % 48;

  // xn slice -> split -> LDS
  {
    const float4* p4 = (const float4*)(ws + OFF_XN + (T0 + tok)*64 + eg*8);
    float4 xa = p4[0], xb = p4[1];
    float xv[8] = {xa.x, xa.y, xa.z, xa.w, xb.x, xb.y, xb.z, xb.w};
    union { unsigned short s[8]; uint2 d[2]; } ph, pl;
    #pragma unroll
    for (int k = 0; k < 8; ++k) split2(xv[k], ph.s[k], pl.s[k]);
    uint2* dh = (uint2*)&XNhi[tok*68 + eg*8];
    uint2* dl = (uint2*)&XNlo[tok*68 + eg*8];
    dh[0] = ph.d[0]; dh[1] = ph.d[1];
    dl[0] = pl.d[0]; dl[1] = pl.d[1];
  }

  // phase0: cls slice in registers (head eg, channels eg*8..+8, 4 regions)
  float cls0[8], cls1[8], cls2[8], cls3[8];
  {
    float ec = ws[OFF_ECLS + b*8 + eg];
    const float* P = ws + OFF_PG + ((long)(b*8 + eg))*21609;
    int p_ij  = (i2*49 + j2)*9;
    int p_ij1 = p_ij + 9;
    int p_iW  = (i2*49 + 48)*9;
    int p_1j  = ((i2+1)*49 + j2)*9;
    int p_1j1 = p_1j + 9;
    int p_1W  = ((i2+1)*49 + 48)*9;
    int p_Hj  = (48*49 + j2)*9;
    int p_Hj1 = p_Hj + 9;
    int p_HW  = (48*49 + 48)*9;
    float rden[4];
    {
      float tl = P[p_1j1];
      float tr = P[p_1W] - P[p_1j];
      float bl = P[p_Hj1] - P[p_ij1];
      float br = P[p_HW] - P[p_iW] - P[p_Hj] + P[p_ij];
      rden[0] = 1.0f/(ec + tl); rden[1] = 1.0f/(ec + tr);
      rden[2] = 1.0f/(ec + bl); rden[3] = 1.0f/(ec + br);
    }
    #pragma unroll
    for (int u = 0; u < 8; ++u) {
      int c = 1 + u;
      float tl = P[p_1j1 + c];
      float tr = P[p_1W + c] - P[p_1j + c];
      float bl = P[p_Hj1 + c] - P[p_ij1 + c];
      float br = P[p_HW + c] - P[p_iW + c] - P[p_Hj + c] + P[p_ij + c];
      float nv = ec * ws[OFF_VC + eg*8 + u];
      cls0[u] = (nv + tl) * rden[0];
      cls1[u] = (nv + tr) * rden[1];
      cls2[u] = (nv + bl) * rden[2];
      cls3[u] = (nv + br) * rden[3];
    }
  }
  __syncthreads();

  const unsigned short* gball = (const unsigned short*)(ws + OFF_GB);
  const unsigned short* zball = (const unsigned short*)(ws + OFF_ZB);

  f32x4 oa0 = {0.f,0.f,0.f,0.f};
  f32x4 oa1 = {0.f,0.f,0.f,0.f};

  const unsigned short* arh = XNhi + (rowblk*16 + lrow)*68;
  const unsigned short* arl = XNlo + (rowblk*16 + lrow)*68;
  const unsigned short* crh = CBhi + (rowblk*16 + lrow)*68;
  const unsigned short* crl = CBlo + (rowblk*16 + lrow)*68;

  for (int hh = 0; hh < 8; ++hh) {
    const unsigned short* gh = gball + hh*8192;
    const unsigned short* zh = zball + hh*8192;
    // ---- stage1: T = XN @ G_h (+v2) ----
    {
      union { bf16x8 v; uint2 d[2]; } ah0, ah1, al0, al1;
      ah0.d[0] = *(const uint2*)(arh + quad*8);      ah0.d[1] = *(const uint2*)(arh + quad*8 + 4);
      ah1.d[0] = *(const uint2*)(arh + 32 + quad*8); ah1.d[1] = *(const uint2*)(arh + 32 + quad*8 + 4);
      al0.d[0] = *(const uint2*)(arl + quad*8);      al0.d[1] = *(const uint2*)(arl + quad*8 + 4);
      al1.d[0] = *(const uint2*)(arl + 32 + quad*8); al1.d[1] = *(const uint2*)(arl + 32 + quad*8 + 4);
      #pragma unroll
      for (int c = 0; c < 2; ++c) {
        int e0 = (colb0 + c)*16 + lrow;
        const unsigned short* gc = gh + e0*64 + quad*8;
        bf16x8 bh0 = *(const bf16x8*)(gc);
        bf16x8 bh1 = *(const bf16x8*)(gc + 32);
        bf16x8 bl0 = *(const bf16x8*)(gc + 4096);
        bf16x8 bl1 = *(const bf16x8*)(gc + 4096 + 32);
        f32x4 acc = {0.f,0.f,0.f,0.f};
        acc = __builtin_amdgcn_mfma_f32_16x16x32_bf16(ah0.v, bh0, acc, 0, 0, 0);
        acc = __builtin_amdgcn_mfma_f32_16x16x32_bf16(ah1.v, bh1, acc, 0, 0, 0);
        acc = __builtin_amdgcn_mfma_f32_16x16x32_bf16(al0.v, bh0, acc, 0, 0, 0);
        acc = __builtin_amdgcn_mfma_f32_16x16x32_bf16(al1.v, bh1, acc, 0, 0, 0);
        acc = __builtin_amdgcn_mfma_f32_16x16x32_bf16(ah0.v, bl0, acc, 0, 0, 0);
        acc = __builtin_amdgcn_mfma_f32_16x16x32_bf16(ah1.v, bl1, acc, 0, 0, 0);
        float v2v = ws[OFF_V2 + hh*64 + e0];
        #pragma unroll
        for (int r = 0; r < 4; ++r)
          Tlds[(rowblk*16 + quad*4 + r)*68 + e0] = acc[r] + v2v;
      }
    }
    __syncthreads();
    // ---- stage2: scores -> softmax -> cbar -> split to LDS ----
    {
      const float4* tp = (const float4*)&Tlds[tok*68 + eg*8];
      float4 ta = tp[0], tb = tp[1];
      float tv[8] = {ta.x, ta.y, ta.z, ta.w, tb.x, tb.y, tb.z, tb.w};
      float p0 = 0.f, p1 = 0.f, p2 = 0.f, p3 = 0.f;
      #pragma unroll
      for (int k = 0; k < 8; ++k) {
        p0 += tv[k]*cls0[k]; p1 += tv[k]*cls1[k];
        p2 += tv[k]*cls2[k]; p3 += tv[k]*cls3[k];
      }
      #pragma unroll
      for (int mk = 1; mk < 8; mk <<= 1) {
        p0 += __shfl_xor(p0, mk, 8);
        p1 += __shfl_xor(p1, mk, 8);
        p2 += __shfl_xor(p2, mk, 8);
        p3 += __shfl_xor(p3, mk, 8);
      }
      float s0 = p0*SCALE_RA, s1 = p1*SCALE_RA, s2 = p2*SCALE_RA, s3 = p3*SCALE_RA;
      float mm = fmaxf(fmaxf(s0, s1), fmaxf(s2, s3));
      float e0 = expf(s0-mm), e1 = expf(s1-mm), e2 = expf(s2-mm), e3 = expf(s3-mm);
      float inv = 1.0f/(e0+e1+e2+e3);
      float av0 = e0*inv, av1 = e1*inv, av2 = e2*inv, av3 = e3*inv;
      union { unsigned short s[8]; uint2 d[2]; } ch, cl;
      #pragma unroll
      for (int k = 0; k < 8; ++k) {
        float cv = av0*cls0[k] + av1*cls1[k] + av2*cls2[k] + av3*cls3[k];
        split2(cv, ch.s[k], cl.s[k]);
      }
      uint2* dh = (uint2*)&CBhi[tok*68 + eg*8];
      uint2* dl = (uint2*)&CBlo[tok*68 + eg*8];
      dh[0] = ch.d[0]; dh[1] = ch.d[1];
      dl[0] = cl.d[0]; dl[1] = cl.d[1];
    }
    __syncthreads();
    // ---- stage3: OUT += CBAR @ Z_h^T ----
    {
      union { bf16x8 v; uint2 d[2]; } ah0, ah1, al0, al1;
      ah0.d[0] = *(const uint2*)(crh + quad*8);      ah0.d[1] = *(const uint2*)(crh + quad*8 + 4);
      ah1.d[0] = *(const uint2*)(crh + 32 + quad*8); ah1.d[1] = *(const uint2*)(crh + 32 + quad*8 + 4);
      al0.d[0] = *(const uint2*)(crl + quad*8);      al0.d[1] = *(const uint2*)(crl + quad*8 + 4);
      al1.d[0] = *(const uint2*)(crl + 32 + quad*8); al1.d[1] = *(const uint2*)(crl + 32 + quad*8 + 4);
      #pragma unroll
      for (int c = 0; c < 2; ++c) {
        int e0 = (colb0 + c)*16 + lrow;
        const unsigned short* zc = zh + e0*64 + quad*8;
        bf16x8 bh0 = *(const bf16x8*)(zc);
        bf16x8 bh1 = *(const bf16x8*)(zc + 32);
        bf16x8 bl0 = *(const bf16x8*)(zc + 4096);
        bf16x8 bl1 = *(const bf16x8*)(zc + 4096 + 32);
        f32x4 acc = (c == 0) ? oa0 : oa1;
        acc = __builtin_amdgcn_mfma_f32_16x16x32_bf16(ah0.v, bh0, acc, 0, 0, 0);
        acc = __builtin_amdgcn_mfma_f32_16x16x32_bf16(ah1.v, bh1, acc, 0, 0, 0);
        acc = __builtin_amdgcn_mfma_f32_16x16x32_bf16(al0.v, bh0, acc, 0, 0, 0);
        acc = __builtin_amdgcn_mfma_f32_16x16x32_bf16(al1.v, bh1, acc, 0, 0, 0);
        acc = __builtin_amdgcn_mfma_f32_16x16x32_bf16(ah0.v, bl0, acc, 0, 0, 0);
        acc = __builtin_amdgcn_mfma_f32_16x16x32_bf16(ah1.v, bl1, acc, 0, 0, 0);
        if (c == 0) oa0 = acc; else oa1 = acc;
      }
    }
  }
  // epilogue
  #pragma unroll
  for (int c = 0; c < 2; ++c) {
    int e0 = (colb0 + c)*16 + lrow;
    float cov = ws[OFF_C1 + e0];
    f32x4 oa = (c == 0) ? oa0 : oa1;
    #pragma unroll
    for (int r = 0; r < 4; ++r)
      outp[(T0 + rowblk*16 + quad*4 + r)*64 + e0] = oa[r] + cov;
  }
}

extern "C" void kernel_launch(void* const* d_in, const int* in_sizes, int n_in,
                              void* d_out, int out_size, void* d_ws, size_t ws_size,
                              hipStream_t stream) {
  const float* x      = (const float*)d_in[0];
  const float* ln_g   = (const float*)d_in[1];
  const float* ln_b   = (const float*)d_in[2];
  const float* Wqkv   = (const float*)d_in[3];
  const float* bqkv   = (const float*)d_in[4];
  const float* cls_tok= (const float*)d_in[5];
  const float* Wwqkv  = (const float*)d_in[6];
  const float* bwqkv  = (const float*)d_in[7];
  const float* Wwproj = (const float*)d_in[8];
  const float* bwproj = (const float*)d_in[9];
  const float* Wraq   = (const float*)d_in[10];
  const float* Wrak   = (const float*)d_in[11];
  const float* Wrav   = (const float*)d_in[12];
  const float* Wrao   = (const float*)d_in[13];
  const float* brao   = (const float*)d_in[14];
  const float* Wout   = (const float*)d_in[15];
  const float* bout   = (const float*)d_in[16];
  float* ws = (float*)d_ws;
  float* outp = (float*)d_out;

  hipLaunchKernelGGL(k_setup1, dim3(1), dim3(256), 0, stream,
                     Wqkv, bqkv, cls_tok, Wwqkv, bwqkv, Wwproj, bwproj,
                     Wraq, Wrak, Wrav, Wrao, brao, Wout, bout, ws);
  hipLaunchKernelGGL(k_setup2, dim3(2), dim3(256), 0, stream, Wraq, Wrak, Wrav, Wwproj, ws);
  hipLaunchKernelGGL(k_setup3, dim3(2), dim3(256), 0, stream, Wwproj, Wrao, ws);
  hipLaunchKernelGGL(k_setup4, dim3(16), dim3(256), 0, stream, Wqkv, Wout, ws);
  hipLaunchKernelGGL(k_lnkv, dim3(2304), dim3(256), 0, stream, x, ln_g, ln_b, Wwqkv, bwqkv, ws);
  hipLaunchKernelGGL(k_prefix, dim3(1024), dim3(256), 0, stream, ws);
  hipLaunchKernelGGL(k_setup5, dim3(16), dim3(256), 0, stream, ws);   // after k_prefix: overlays dead k_t
  hipLaunchKernelGGL(k_main, dim3(4608), dim3(256), 0, stream, ws, outp);
}

// Round 5
// 590.845 us; speedup vs baseline: 2.3571x; 1.0927x over previous
//
#include <hip/hip_runtime.h>
#include <math.h>

// FourRegionAttention on MI355X (gfx950). B=64, n=2304 (48x48), D=64, h=8, hd=8.
// k_main: 2-heads-per-iteration MFMA (16x16x32 bf16, hi/lo 3-product fp32
// emulation); 9 barriers/block. Setup collapsed to 2 kernels.

#define SCALE_W  0.3535533905932738f   // 8^-0.5
#define SCALE_RA 0.3535533905932738f
#define LN_EPS 1e-5f

typedef __attribute__((ext_vector_type(8))) short bf16x8;
typedef __attribute__((ext_vector_type(4))) float f32x4;

// ---- workspace layout (float offsets) ----
#define OFF_XN   0ull
#define SZ_XN    (64ull*2304*64)            // 9437184
#define OFF_KT   (OFF_XN + SZ_XN)           // k_t [b][h][n][8]
#define SZ_KT    (64ull*8*2304*8)           // 9437184
#define OFF_VT   (OFF_KT + SZ_KT)           // v_t [b][h][n][8]
#define OFF_PG   (OFF_VT + SZ_KT)           // P [b][h][49][49][9]
#define SZ_PG    (512ull*49*49*9)           // 11063808
#define OFF_ECLS (OFF_PG + SZ_PG)           // 512
#define OFF_QC   (OFF_ECLS + 512)           // 64 (scaled q_c)
#define OFF_KC   (OFF_QC + 64)              // 64
#define OFF_VC   (OFF_KC + 64)              // 64
#define OFF_CLOG (OFF_VC + 64)              // 8
#define OFF_BK   (OFF_CLOG + 8)             // 64
#define OFF_BV   (OFF_BK + 64)              // 64
#define OFF_AH   (OFF_BV + 64)              // 512 a_h = Wraq@bqkv_h
#define OFF_W1   (OFF_AH + 512)             // 64  Wraq^T@bk
#define OFF_WZ   (OFF_W1 + 64)              // 64  Wrao@bv
#define OFF_B2   (OFF_WZ + 64)              // 512 Wrak^T@a_h
#define OFF_V2   (OFF_B2 + 512)             // 512 v2_h
#define OFF_UH   (OFF_V2 + 512)             // 512 (unused in k_main)
#define OFF_CH   (OFF_UH + 512)             // 8   (unused in k_main)
#define OFF_C1   (OFF_CH + 8)               // 64  const output bias
#define OFF_G    (OFF_C1 + 64)              // 32768 floats -> GB: [h][split][e][d] ushorts
#define OFF_Z    (OFF_G + 32768)            // 32768 floats -> ZB: [h][split][e][d] ushorts

__device__ inline void split2(float x, unsigned short &h, unsigned short &l) {
  unsigned u = __float_as_uint(x);
  unsigned hr = (u + 0x7fffu + ((u >> 16) & 1u)) >> 16;
  h = (unsigned short)hr;
  float hf = __uint_as_float(hr << 16);
  float lo = x - hf;
  unsigned u2 = __float_as_uint(lo);
  l = (unsigned short)((u2 + 0x7fffu + ((u2 >> 16) & 1u)) >> 16);
}

// ---------------- setup kernel 1: small folded vectors ----------------
__global__ void k_setup1(const float* __restrict__ Wqkv, const float* __restrict__ bqkv,
                         const float* __restrict__ cls_tok, const float* __restrict__ Wwqkv,
                         const float* __restrict__ bwqkv, const float* __restrict__ Wwproj,
                         const float* __restrict__ bwproj, const float* __restrict__ Wraq,
                         const float* __restrict__ Wrak, const float* __restrict__ Wrav,
                         const float* __restrict__ Wrao, const float* __restrict__ brao,
                         const float* __restrict__ Wout, const float* __restrict__ bout,
                         float* __restrict__ ws) {
  int tid = threadIdx.x;
  for (int idx = tid; idx < 832; idx += 256) {
    if (idx < 192) {
      float s = bwqkv[idx];
      for (int d = 0; d < 64; ++d) s += cls_tok[d] * Wwqkv[idx*64 + d];
      if (idx < 64) ws[OFF_QC + idx] = s * SCALE_W;
      else if (idx < 128) ws[OFF_KC + idx - 64] = s;
      else ws[OFF_VC + idx - 128] = s;
    } else if (idx < 256) {
      int e = idx - 192; float s = 0.f;
      for (int d = 0; d < 64; ++d) s += Wrak[e*64+d] * bwproj[d];
      ws[OFF_BK + e] = s;
    } else if (idx < 320) {
      int e = idx - 256; float s = 0.f;
      for (int d = 0; d < 64; ++d) s += Wrav[e*64+d] * bwproj[d];
      ws[OFF_BV + e] = s;
    } else {
      int t2 = idx - 320; int hh = t2 >> 6, e = t2 & 63; float s = 0.f;
      for (int d = 0; d < 64; ++d) s += Wraq[e*64+d] * bqkv[hh*64+d];
      ws[OFF_AH + t2] = s;
    }
  }
  __syncthreads();
  for (int idx = tid; idx < 656; idx += 256) {
    if (idx < 8) {
      float s = 0.f;
      for (int u = 0; u < 8; ++u) s += ws[OFF_QC + idx*8+u] * ws[OFF_KC + idx*8+u];
      ws[OFF_CLOG + idx] = s;
    } else if (idx < 72) {
      int e = idx - 8; float s = 0.f;
      for (int d = 0; d < 64; ++d) s += Wraq[d*64+e] * ws[OFF_BK + d];
      ws[OFF_W1 + e] = s;
    } else if (idx < 136) {
      int e = idx - 72; float s = 0.f;
      for (int d = 0; d < 64; ++d) s += Wrao[e*64+d] * ws[OFF_BV + d];
      ws[OFF_WZ + e] = s;
    } else if (idx < 648) {
      int t2 = idx - 136; int hh = t2 >> 6, e = t2 & 63; float s = 0.f;
      for (int d = 0; d < 64; ++d) s += Wrak[d*64+e] * ws[OFF_AH + hh*64+d];
      ws[OFF_B2 + t2] = s;
    } else {
      int hh = idx - 648; float s = 0.f;
      for (int e = 0; e < 64; ++e) s += ws[OFF_AH + hh*64+e] * ws[OFF_BK + e];
      ws[OFF_CH + hh] = s;
    }
  }
  __syncthreads();
  for (int idx = tid; idx < 1088; idx += 256) {
    if (idx < 512) {
      int hh = idx >> 6, e = idx & 63; float s = 0.f;
      for (int d = 0; d < 64; ++d) s += Wwproj[d*64+e] * ws[OFF_B2 + hh*64+d];
      ws[OFF_V2 + idx] = s;
    } else if (idx < 1024) {
      int t2 = idx - 512; int hh = t2 >> 6, e = t2 & 63; float s = 0.f;
      for (int d = 0; d < 64; ++d) s += Wqkv[(hh*64+d)*64 + e] * ws[OFF_W1 + d];
      ws[OFF_UH + t2] = s;
    } else {
      int e = idx - 1024; float s = bout[e];
      for (int f = 0; f < 512; ++f)
        s += Wout[e*512+f] * (brao[f & 63] + ws[OFF_WZ + (f & 63)]);
      ws[OFF_C1 + e] = s;
    }
  }
}

// ---------------- setup kernel W: per-head G/Z chains -> split bf16 ----------------
// grid 16: blk<8 -> G_h path, blk>=8 -> Z_h path. Each block computes its 64x64
// chain redundantly in LDS, emits GB/ZB [h][split][e][d] ushorts.
__global__ __launch_bounds__(256) void k_setupW(const float* __restrict__ Wqkv,
      const float* __restrict__ Wraq, const float* __restrict__ Wrak,
      const float* __restrict__ Wrav, const float* __restrict__ Wrao,
      const float* __restrict__ Wwproj, const float* __restrict__ Wout,
      float* __restrict__ ws) {
  __shared__ float A[64*65];
  __shared__ float Bl[64*65];
  int tid = threadIdx.x;
  int blk = blockIdx.x;
  if (blk < 8) {
    int hh = blk;
    // step1: KQ[d][e] = sum_f Wraq[f][d]*Wrak[f][e]
    for (int o = tid; o < 4096; o += 256) {
      int d = o & 63, e = o >> 6; float s = 0.f;
      for (int f = 0; f < 64; ++f) s += Wraq[f*64+d] * Wrak[f*64+e];
      A[d*65 + e] = s;
    }
    __syncthreads();
    // step2: KQP[i][j] = sum_f KQ[i][f]*Wwproj[f][j]
    for (int o = tid; o < 4096; o += 256) {
      int j = o & 63, i = o >> 6; float s = 0.f;
      for (int f = 0; f < 64; ++f) s += A[i*65 + f] * Wwproj[f*64 + j];
      Bl[i*65 + j] = s;
    }
    __syncthreads();
    // step3: G[d][e] = sum_f Wqkv[(h*64+f)][d]*KQP[f][e] -> GB[h][split][e][d]
    unsigned short* gb = (unsigned short*)(ws + OFF_G) + hh*8192;
    for (int o = tid; o < 4096; o += 256) {
      int d = o & 63, e = o >> 6; float s = 0.f;
      for (int f = 0; f < 64; ++f) s += Wqkv[(hh*64+f)*64 + d] * Bl[f*65 + e];
      unsigned short h16, l16;
      split2(s, h16, l16);
      gb[e*64 + d] = h16;
      gb[4096 + e*64 + d] = l16;
    }
  } else {
    int hh = blk - 8;
    // step1: WVE[e][d] = sum_f Wrav[e][f]*Wwproj[f][d]
    for (int o = tid; o < 4096; o += 256) {
      int d = o & 63, e = o >> 6; float s = 0.f;
      for (int f = 0; f < 64; ++f) s += Wrav[e*64+f] * Wwproj[f*64+d];
      A[e*65 + d] = s;
    }
    __syncthreads();
    // step2: RW[i][d] = sum_f Wrao[i][f]*WVE[f][d]
    for (int o = tid; o < 4096; o += 256) {
      int d = o & 63, i = o >> 6; float s = 0.f;
      for (int f = 0; f < 64; ++f) s += Wrao[i*64+f] * A[f*65 + d];
      Bl[i*65 + d] = s;
    }
    __syncthreads();
    // step3: Zt[d][e] = Z_h[e][d] = sum_f Wout[e][h*64+f]*RW[f][d] -> ZB[h][split][e][d]
    unsigned short* zb = (unsigned short*)(ws + OFF_Z) + hh*8192;
    for (int o = tid; o < 4096; o += 256) {
      int d = o & 63, e = o >> 6; float s = 0.f;
      for (int f = 0; f < 64; ++f) s += Wout[e*512 + hh*64 + f] * Bl[f*65 + d];
      unsigned short h16, l16;
      split2(s, h16, l16);
      zb[e*64 + d] = h16;
      zb[4096 + e*64 + d] = l16;
    }
  }
}

// ---------------- LayerNorm + k/v GEMM ----------------
__global__ __launch_bounds__(256) void k_lnkv(const float* __restrict__ x,
      const float* __restrict__ ln_g, const float* __restrict__ ln_b,
      const float* __restrict__ Wwqkv, const float* __restrict__ bwqkv,
      float* __restrict__ ws) {
  __shared__ float sm[4352 + 8448 + 128];
  float* xnT = sm;                // [d][68]
  float* xt  = sm + 4352;         // [tok][65]
  float* wkv = sm + 4352;         // [d][132]
  float* muL = sm + 4352 + 8448;
  float* rsL = muL + 64;

  int tid = threadIdx.x;
  long T0 = (long)blockIdx.x * 64;
  int tok = tid >> 2, seg = tid & 3;

  const float4* x4 = (const float4*)(x + (T0 + tok)*64 + seg*16);
  float4 va = x4[0], vb = x4[1], vc4 = x4[2], vd = x4[3];
  {
    float* xp = xt + tok*65 + seg*16;
    xp[0]=va.x; xp[1]=va.y; xp[2]=va.z; xp[3]=va.w;
    xp[4]=vb.x; xp[5]=vb.y; xp[6]=vb.z; xp[7]=vb.w;
    xp[8]=vc4.x; xp[9]=vc4.y; xp[10]=vc4.z; xp[11]=vc4.w;
    xp[12]=vd.x; xp[13]=vd.y; xp[14]=vd.z; xp[15]=vd.w;
  }
  __syncthreads();
  if (tid < 64) {
    float s = 0.f;
    for (int i2 = 0; i2 < 64; ++i2) s += xt[tid*65 + i2];
    float mu = s * (1.0f/64.0f);
    float v = 0.f;
    for (int i2 = 0; i2 < 64; ++i2) { float d = xt[tid*65 + i2] - mu; v += d*d; }
    v *= (1.0f/64.0f);
    muL[tid] = mu; rsL[tid] = 1.0f / sqrtf(v + LN_EPS);
  }
  __syncthreads();
  {
    float mu = muL[tok], rs = rsL[tok];
    float xv[16];
    #pragma unroll
    for (int k = 0; k < 16; ++k) {
      int i2 = seg*16 + k;
      float v = (xt[tok*65 + i2] - mu) * rs * ln_g[i2] + ln_b[i2];
      xv[k] = v;
      xnT[i2*68 + tok] = v;
    }
    float4* xng = (float4*)(ws + OFF_XN + (T0 + tok)*64 + seg*16);
    xng[0] = make_float4(xv[0], xv[1], xv[2], xv[3]);
    xng[1] = make_float4(xv[4], xv[5], xv[6], xv[7]);
    xng[2] = make_float4(xv[8], xv[9], xv[10], xv[11]);
    xng[3] = make_float4(xv[12], xv[13], xv[14], xv[15]);
  }
  __syncthreads();
  {
    int o = tid >> 1, dh = (tid & 1) * 32;
    #pragma unroll
    for (int k = 0; k < 32; k += 4) {
      float4 w4 = *(const float4*)(Wwqkv + (64 + o)*64 + dh + k);
      wkv[(dh+k+0)*132 + o] = w4.x;
      wkv[(dh+k+1)*132 + o] = w4.y;
      wkv[(dh+k+2)*132 + o] = w4.z;
      wkv[(dh+k+3)*132 + o] = w4.w;
    }
  }
  __syncthreads();
  int tokq = tid & 15, og = tid >> 4;
  float acc[4][8];
  #pragma unroll
  for (int ti = 0; ti < 4; ++ti)
    #pragma unroll
    for (int k = 0; k < 8; ++k) acc[ti][k] = 0.f;
  for (int d2 = 0; d2 < 64; ++d2) {
    float4 a4 = *(float4*)&xnT[d2*68 + tokq*4];
    float4 b0 = *(float4*)&wkv[d2*132 + og*8];
    float4 b1 = *(float4*)&wkv[d2*132 + og*8 + 4];
    float aa[4] = {a4.x, a4.y, a4.z, a4.w};
    float bbv[8] = {b0.x,b0.y,b0.z,b0.w,b1.x,b1.y,b1.z,b1.w};
    #pragma unroll
    for (int ti = 0; ti < 4; ++ti)
      #pragma unroll
      for (int k = 0; k < 8; ++k) acc[ti][k] += aa[ti]*bbv[k];
  }
  int hh2 = og & 7;
  float bsv[8];
  #pragma unroll
  for (int k = 0; k < 8; ++k) bsv[k] = bwqkv[64 + og*8 + k];
  unsigned long long dstoff = (og < 8) ? OFF_KT : OFF_VT;
  #pragma unroll
  for (int ti = 0; ti < 4; ++ti) {
    long ntok = T0 + tokq*4 + ti;
    int bb = (int)(ntok / 2304);
    int nl = (int)(ntok % 2304);
    float* dst = ws + dstoff + ((long)(bb*8 + hh2)*2304 + nl)*8;
    *(float4*)dst = make_float4(acc[ti][0]+bsv[0], acc[ti][1]+bsv[1], acc[ti][2]+bsv[2], acc[ti][3]+bsv[3]);
    *(float4*)(dst+4) = make_float4(acc[ti][4]+bsv[4], acc[ti][5]+bsv[5], acc[ti][6]+bsv[6], acc[ti][7]+bsv[7]);
  }
}

// ---------------- logits + softmax-normalizer + 2D prefix sums ----------------
__global__ __launch_bounds__(256) void k_prefix(float* __restrict__ ws) {
  __shared__ float lg[2304];
  __shared__ float Pp[49*49*5];
  __shared__ float red[256];
  int tid = threadIdx.x;
  int blk = blockIdx.x;
  int g = blk & 1, bh = blk >> 1;
  int hh = bh & 7;
  const float* kt = ws + OFF_KT + (long)bh*2304*8;
  const float* vt = ws + OFF_VT + (long)bh*2304*8 + (g ? 4 : 0);
  float qc[8];
  #pragma unroll
  for (int u = 0; u < 8; ++u) qc[u] = ws[OFF_QC + hh*8 + u];
  float mloc = -1e30f;
  #pragma unroll
  for (int it = 0; it < 9; ++it) {
    int nn = tid + it*256;
    const float4* kk = (const float4*)(kt + nn*8);
    float4 k0 = kk[0], k1 = kk[1];
    float lv = qc[0]*k0.x + qc[1]*k0.y + qc[2]*k0.z + qc[3]*k0.w
             + qc[4]*k1.x + qc[5]*k1.y + qc[6]*k1.z + qc[7]*k1.w;
    lg[nn] = lv;
    mloc = fmaxf(mloc, lv);
  }
  red[tid] = mloc;
  __syncthreads();
  for (int s2 = 128; s2 > 0; s2 >>= 1) {
    if (tid < s2) red[tid] = fmaxf(red[tid], red[tid + s2]);
    __syncthreads();
  }
  float m = fmaxf(red[0], ws[OFF_CLOG + hh]);
  if (tid == 0 && g == 0) ws[OFF_ECLS + bh] = expf(ws[OFF_CLOG + hh] - m);
  #pragma unroll
  for (int it = 0; it < 9; ++it) {
    int nn = tid + it*256;
    lg[nn] = expf(lg[nn] - m);
  }
  for (int idx = tid; idx < 49*49*5; idx += 256) Pp[idx] = 0.f;
  __syncthreads();
  int nc = g ? 4 : 5;
  #pragma unroll
  for (int it = 0; it < 9; ++it) {
    int nn = tid + it*256;
    int i2 = nn / 48, j2 = nn % 48;
    float ev = lg[nn];
    float4 v4 = *(const float4*)(vt + nn*8);
    float* cell = &Pp[((i2+1)*49 + (j2+1))*5];
    if (g == 0) {
      cell[0] = ev; cell[1] = ev*v4.x; cell[2] = ev*v4.y; cell[3] = ev*v4.z; cell[4] = ev*v4.w;
    } else {
      cell[0] = ev*v4.x; cell[1] = ev*v4.y; cell[2] = ev*v4.z; cell[3] = ev*v4.w;
    }
  }
  __syncthreads();
  for (int idx = tid; idx < 48*nc; idx += 256) {
    int j2 = idx / nc + 1, c = idx % nc;
    for (int i2 = 2; i2 <= 48; ++i2)
      Pp[(i2*49 + j2)*5 + c] += Pp[((i2-1)*49 + j2)*5 + c];
  }
  __syncthreads();
  for (int idx = tid; idx < 48*nc; idx += 256) {
    int i2 = idx / nc + 1, c = idx % nc;
    for (int j2 = 2; j2 <= 48; ++j2)
      Pp[(i2*49 + j2)*5 + c] += Pp[(i2*49 + j2 - 1)*5 + c];
  }
  __syncthreads();
  float* pg = ws + OFF_PG + (long)bh*21609;
  int tot = 2401 * nc;
  for (int idx = tid; idx < tot; idx += 256) {
    int cell2 = idx / nc, c = idx % nc;
    pg[cell2*9 + (g ? 5 + c : c)] = Pp[cell2*5 + c];
  }
}

// ---------------- main fused kernel (MFMA, 2 heads/iter) ----------------
// grid 4608 x 256 threads, 32 tokens/block. LDS 42496 B -> 3 blocks/CU.
__global__ __launch_bounds__(256) void k_main(const float* __restrict__ ws,
                                              float* __restrict__ outp) {
  __shared__ __align__(16) unsigned short XNhi[32*68];
  __shared__ __align__(16) unsigned short XNlo[32*68];
  __shared__ __align__(16) unsigned short CBhi[32*132];
  __shared__ __align__(16) unsigned short CBlo[32*132];
  __shared__ __align__(16) float Tlds[32*132];

  int tid = threadIdx.x;
  int tok = tid >> 3, eg = tid & 7;
  int lane = tid & 63, wv = tid >> 6;
  int quad = lane >> 4, lrow = lane & 15;
  int rowblk = wv >> 1, wcol = wv & 1;
  long T0 = (long)blockIdx.x * 32;
  int b = (int)(T0 / 2304);
  int n = (int)(T0 % 2304) + tok;
  int i2 = n / 48, j2 = n % 48;

  // xn slice -> split -> LDS
  {
    const float4* p4 = (const float4*)(ws + OFF_XN + (T0 + tok)*64 + eg*8);
    float4 xa = p4[0], xb = p4[1];
    float xv[8] = {xa.x, xa.y, xa.z, xa.w, xb.x, xb.y, xb.z, xb.w};
    union { unsigned short s[8]; uint2 d[2]; } ph, pl;
    #pragma unroll
    for (int k = 0; k < 8; ++k) split2(xv[k], ph.s[k], pl.s[k]);
    uint2* dh = (uint2*)&XNhi[tok*68 + eg*8];
    uint2* dl = (uint2*)&XNlo[tok*68 + eg*8];
    dh[0] = ph.d[0]; dh[1] = ph.d[1];
    dl[0] = pl.d[0]; dl[1] = pl.d[1];
  }

  // phase0: cls slice in registers (source-head eg, channels eg*8..+8, 4 regions)
  float cls0[8], cls1[8], cls2[8], cls3[8];
  {
    float ec = ws[OFF_ECLS + b*8 + eg];
    const float* P = ws + OFF_PG + ((long)(b*8 + eg))*21609;
    int p_ij  = (i2*49 + j2)*9;
    int p_ij1 = p_ij + 9;
    int p_iW  = (i2*49 + 48)*9;
    int p_1j  = ((i2+1)*49 + j2)*9;
    int p_1j1 = p_1j + 9;
    int p_1W  = ((i2+1)*49 + 48)*9;
    int p_Hj  = (48*49 + j2)*9;
    int p_Hj1 = p_Hj + 9;
    int p_HW  = (48*49 + 48)*9;
    float rden[4];
    {
      float tl = P[p_1j1];
      float tr = P[p_1W] - P[p_1j];
      float bl = P[p_Hj1] - P[p_ij1];
      float br = P[p_HW] - P[p_iW] - P[p_Hj] + P[p_ij];
      rden[0] = 1.0f/(ec + tl); rden[1] = 1.0f/(ec + tr);
      rden[2] = 1.0f/(ec + bl); rden[3] = 1.0f/(ec + br);
    }
    #pragma unroll
    for (int u = 0; u < 8; ++u) {
      int c = 1 + u;
      float tl = P[p_1j1 + c];
      float tr = P[p_1W + c] - P[p_1j + c];
      float bl = P[p_Hj1 + c] - P[p_ij1 + c];
      float br = P[p_HW + c] - P[p_iW + c] - P[p_Hj + c] + P[p_ij + c];
      float nv = ec * ws[OFF_VC + eg*8 + u];
      cls0[u] = (nv + tl) * rden[0];
      cls1[u] = (nv + tr) * rden[1];
      cls2[u] = (nv + bl) * rden[2];
      cls3[u] = (nv + br) * rden[3];
    }
  }
  __syncthreads();

  const unsigned short* gball = (const unsigned short*)(ws + OFF_G);
  const unsigned short* zball = (const unsigned short*)(ws + OFF_Z);

  f32x4 oa0 = {0.f,0.f,0.f,0.f};
  f32x4 oa1 = {0.f,0.f,0.f,0.f};

  const unsigned short* arh = XNhi + (rowblk*16 + lrow)*68;
  const unsigned short* arl = XNlo + (rowblk*16 + lrow)*68;
  const unsigned short* crh = CBhi + (rowblk*16 + lrow)*132;
  const unsigned short* crl = CBlo + (rowblk*16 + lrow)*132;

  for (int it = 0; it < 4; ++it) {
    int h0 = it*2;
    // ---- stage1: T[32x128] = XN @ [G_h0 | G_h1] (+v2) ----
    {
      union { bf16x8 v; uint2 d[2]; } ah0, ah1, al0, al1;
      ah0.d[0] = *(const uint2*)(arh + quad*8);      ah0.d[1] = *(const uint2*)(arh + quad*8 + 4);
      ah1.d[0] = *(const uint2*)(arh + 32 + quad*8); ah1.d[1] = *(const uint2*)(arh + 32 + quad*8 + 4);
      al0.d[0] = *(const uint2*)(arl + quad*8);      al0.d[1] = *(const uint2*)(arl + quad*8 + 4);
      al1.d[0] = *(const uint2*)(arl + 32 + quad*8); al1.d[1] = *(const uint2*)(arl + 32 + quad*8 + 4);
      #pragma unroll
      for (int c = 0; c < 4; ++c) {
        int colb = wcol*4 + c;                  // 0..7
        int e0 = colb*16 + lrow;                // 0..127
        const unsigned short* gh = gball + (h0 + (colb >> 2))*8192 + ((colb & 3)*16 + lrow)*64 + quad*8;
        bf16x8 bh0 = *(const bf16x8*)(gh);
        bf16x8 bh1 = *(const bf16x8*)(gh + 32);
        bf16x8 bl0 = *(const bf16x8*)(gh + 4096);
        bf16x8 bl1 = *(const bf16x8*)(gh + 4096 + 32);
        f32x4 acc = {0.f,0.f,0.f,0.f};
        acc = __builtin_amdgcn_mfma_f32_16x16x32_bf16(ah0.v, bh0, acc, 0, 0, 0);
        acc = __builtin_amdgcn_mfma_f32_16x16x32_bf16(ah1.v, bh1, acc, 0, 0, 0);
        acc = __builtin_amdgcn_mfma_f32_16x16x32_bf16(al0.v, bh0, acc, 0, 0, 0);
        acc = __builtin_amdgcn_mfma_f32_16x16x32_bf16(al1.v, bh1, acc, 0, 0, 0);
        acc = __builtin_amdgcn_mfma_f32_16x16x32_bf16(ah0.v, bl0, acc, 0, 0, 0);
        acc = __builtin_amdgcn_mfma_f32_16x16x32_bf16(ah1.v, bl1, acc, 0, 0, 0);
        float v2v = ws[OFF_V2 + h0*64 + e0];
        #pragma unroll
        for (int r = 0; r < 4; ++r)
          Tlds[(rowblk*16 + quad*4 + r)*132 + e0] = acc[r] + v2v;
      }
    }
    __syncthreads();
    // ---- stage2: both heads' scores -> softmax -> cbar -> split to LDS ----
    {
      float tv0[8], tv1[8];
      {
        const float4* tp0 = (const float4*)&Tlds[tok*132 + eg*8];
        const float4* tp1 = (const float4*)&Tlds[tok*132 + 64 + eg*8];
        float4 a0 = tp0[0], b0 = tp0[1], a1 = tp1[0], b1 = tp1[1];
        tv0[0]=a0.x; tv0[1]=a0.y; tv0[2]=a0.z; tv0[3]=a0.w;
        tv0[4]=b0.x; tv0[5]=b0.y; tv0[6]=b0.z; tv0[7]=b0.w;
        tv1[0]=a1.x; tv1[1]=a1.y; tv1[2]=a1.z; tv1[3]=a1.w;
        tv1[4]=b1.x; tv1[5]=b1.y; tv1[6]=b1.z; tv1[7]=b1.w;
      }
      float p0=0.f,p1=0.f,p2=0.f,p3=0.f,q0=0.f,q1=0.f,q2=0.f,q3=0.f;
      #pragma unroll
      for (int k = 0; k < 8; ++k) {
        p0 += tv0[k]*cls0[k]; p1 += tv0[k]*cls1[k];
        p2 += tv0[k]*cls2[k]; p3 += tv0[k]*cls3[k];
        q0 += tv1[k]*cls0[k]; q1 += tv1[k]*cls1[k];
        q2 += tv1[k]*cls2[k]; q3 += tv1[k]*cls3[k];
      }
      #pragma unroll
      for (int mk = 1; mk < 8; mk <<= 1) {
        p0 += __shfl_xor(p0, mk, 8); p1 += __shfl_xor(p1, mk, 8);
        p2 += __shfl_xor(p2, mk, 8); p3 += __shfl_xor(p3, mk, 8);
        q0 += __shfl_xor(q0, mk, 8); q1 += __shfl_xor(q1, mk, 8);
        q2 += __shfl_xor(q2, mk, 8); q3 += __shfl_xor(q3, mk, 8);
      }
      union { unsigned short s[8]; uint2 d[2]; } ch, cl;
      {
        float s0 = p0*SCALE_RA, s1 = p1*SCALE_RA, s2 = p2*SCALE_RA, s3 = p3*SCALE_RA;
        float mm = fmaxf(fmaxf(s0, s1), fmaxf(s2, s3));
        float e0 = expf(s0-mm), e1 = expf(s1-mm), e2 = expf(s2-mm), e3 = expf(s3-mm);
        float inv = 1.0f/(e0+e1+e2+e3);
        float av0 = e0*inv, av1 = e1*inv, av2 = e2*inv, av3 = e3*inv;
        #pragma unroll
        for (int k = 0; k < 8; ++k) {
          float cv = av0*cls0[k] + av1*cls1[k] + av2*cls2[k] + av3*cls3[k];
          split2(cv, ch.s[k], cl.s[k]);
        }
        uint2* dh = (uint2*)&CBhi[tok*132 + eg*8];
        uint2* dl = (uint2*)&CBlo[tok*132 + eg*8];
        dh[0] = ch.d[0]; dh[1] = ch.d[1];
        dl[0] = cl.d[0]; dl[1] = cl.d[1];
      }
      {
        float s0 = q0*SCALE_RA, s1 = q1*SCALE_RA, s2 = q2*SCALE_RA, s3 = q3*SCALE_RA;
        float mm = fmaxf(fmaxf(s0, s1), fmaxf(s2, s3));
        float e0 = expf(s0-mm), e1 = expf(s1-mm), e2 = expf(s2-mm), e3 = expf(s3-mm);
        float inv = 1.0f/(e0+e1+e2+e3);
        float av0 = e0*inv, av1 = e1*inv, av2 = e2*inv, av3 = e3*inv;
        #pragma unroll
        for (int k = 0; k < 8; ++k) {
          float cv = av0*cls0[k] + av1*cls1[k] + av2*cls2[k] + av3*cls3[k];
          split2(cv, ch.s[k], cl.s[k]);
        }
        uint2* dh = (uint2*)&CBhi[tok*132 + 64 + eg*8];
        uint2* dl = (uint2*)&CBlo[tok*132 + 64 + eg*8];
        dh[0] = ch.d[0]; dh[1] = ch.d[1];
        dl[0] = cl.d[0]; dl[1] = cl.d[1];
      }
    }
    __syncthreads();
    // ---- stage3: OUT(32x64) += CB(32x128) @ [Zt_h0 ; Zt_h1] ----
    {
      #pragma unroll
      for (int c = 0; c < 2; ++c) {
        int colb = wcol*2 + c;                  // 0..3
        int e0 = colb*16 + lrow;                // 0..63
        f32x4 acc = (c == 0) ? oa0 : oa1;
        #pragma unroll
        for (int kb = 0; kb < 4; ++kb) {
          union { bf16x8 v; uint2 d[2]; } ah, al;
          const unsigned short* ch2 = crh + kb*32 + quad*8;
          const unsigned short* cl2 = crl + kb*32 + quad*8;
          ah.d[0] = *(const uint2*)(ch2); ah.d[1] = *(const uint2*)(ch2 + 4);
          al.d[0] = *(const uint2*)(cl2); al.d[1] = *(const uint2*)(cl2 + 4);
          const unsigned short* zc = zball + (h0 + (kb >> 1))*8192 + e0*64 + (kb & 1)*32 + quad*8;
          bf16x8 bh = *(const bf16x8*)(zc);
          bf16x8 bl = *(const bf16x8*)(zc + 4096);
          acc = __builtin_amdgcn_mfma_f32_16x16x32_bf16(ah.v, bh, acc, 0, 0, 0);
          acc = __builtin_amdgcn_mfma_f32_16x16x32_bf16(al.v, bh, acc, 0, 0, 0);
          acc = __builtin_amdgcn_mfma_f32_16x16x32_bf16(ah.v, bl, acc, 0, 0, 0);
        }
        if (c == 0) oa0 = acc; else oa1 = acc;
      }
    }
  }
  // epilogue
  #pragma unroll
  for (int c = 0; c < 2; ++c) {
    int e0 = (wcol*2 + c)*16 + lrow;
    float cov = ws[OFF_C1 + e0];
    f32x4 oa = (c == 0) ? oa0 : oa1;
    #pragma unroll
    for (int r = 0; r < 4; ++r)
      outp[(T0 + rowblk*16 + quad*4 + r)*64 + e0] = oa[r] + cov;
  }
}

extern "C" void kernel_launch(void* const* d_in, const int* in_sizes, int n_in,
                              void* d_out, int out_size, void* d_ws, size_t ws_size,
                              hipStream_t stream) {
  const float* x      = (const float*)d_in[0];
  const float* ln_g   = (const float*)d_in[1];
  const float* ln_b   = (const float*)d_in[2];
  const float* Wqkv   = (const float*)d_in[3];
  const float* bqkv   = (const float*)d_in[4];
  const float* cls_tok= (const float*)d_in[5];
  const float* Wwqkv  = (const float*)d_in[6];
  const float* bwqkv  = (const float*)d_in[7];
  const float* Wwproj = (const float*)d_in[8];
  const float* bwproj = (const float*)d_in[9];
  const float* Wraq   = (const float*)d_in[10];
  const float* Wrak   = (const float*)d_in[11];
  const float* Wrav   = (const float*)d_in[12];
  const float* Wrao   = (const float*)d_in[13];
  const float* brao   = (const float*)d_in[14];
  const float* Wout   = (const float*)d_in[15];
  const float* bout   = (const float*)d_in[16];
  float* ws = (float*)d_ws;
  float* outp = (float*)d_out;

  hipLaunchKernelGGL(k_setup1, dim3(1), dim3(256), 0, stream,
                     Wqkv, bqkv, cls_tok, Wwqkv, bwqkv, Wwproj, bwproj,
                     Wraq, Wrak, Wrav, Wrao, brao, Wout, bout, ws);
  hipLaunchKernelGGL(k_setupW, dim3(16), dim3(256), 0, stream,
                     Wqkv, Wraq, Wrak, Wrav, Wrao, Wwproj, Wout, ws);
  hipLaunchKernelGGL(k_lnkv, dim3(2304), dim3(256), 0, stream, x, ln_g, ln_b, Wwqkv, bwqkv, ws);
  hipLaunchKernelGGL(k_prefix, dim3(1024), dim3(256), 0, stream, ws);
  hipLaunchKernelGGL(k_main, dim3(4608), dim3(256), 0, stream, ws, outp);
}